// Round 9
// baseline (331.489 us; speedup 1.0000x reference)
//
#include <hip/hip_runtime.h>
#include <hip/hip_bf16.h>

typedef __bf16 bf16_t;
typedef __bf16 bf16x8 __attribute__((ext_vector_type(8)));
typedef float  f32x4  __attribute__((ext_vector_type(4)));
typedef int    i32x4  __attribute__((ext_vector_type(4)));

#define M_DIM 4096
#define N_DIM 12288
#define K_DIM 3072
#define NBLK  96      // K_DIM / 32 quant blocks per output row

#define BM 256
#define BN 256
#define BK 64
#define THREADS 512
#define NT (K_DIM / BK)   // 48 K-tiles

// ws layout: W_bf16 [N][K] at 0 (75.5 MB), X_bf16 [M][K] after (25.2 MB)
#define W_BYTES ((size_t)N_DIM * K_DIM * 2)
#define X_BYTES ((size_t)M_DIM * K_DIM * 2)

#define BAR()   asm volatile("s_barrier" ::: "memory")
#define SBAR()  __builtin_amdgcn_sched_barrier(0)
#define LGKM(n) do { asm volatile("s_waitcnt lgkmcnt(" #n ")" ::: "memory"); \
                     __builtin_amdgcn_sched_barrier(0); } while (0)

__device__ __forceinline__ void gload_lds16(const void* g, void* l) {
    // async global->LDS, 16B/lane; LDS dest = wave-uniform base + lane*16
    __builtin_amdgcn_global_load_lds(
        (const __attribute__((address_space(1))) unsigned int*)g,
        (__attribute__((address_space(3))) unsigned int*)l, 16, 0, 0);
}

// ---------------- Pass 1a: dequant Q8_0 weights -> bf16 ----------------
__global__ __launch_bounds__(256) void dequant_w_kernel(
    const int* __restrict__ wq, const float* __restrict__ scales,
    bf16_t* __restrict__ W)
{
    unsigned c = blockIdx.x * 256u + threadIdx.x;   // 8-elem chunk id
    unsigned o  = c / 384u;                         // 384 chunks per row
    unsigned kc = c - o * 384u;
    float s = scales[o * NBLK + (kc >> 2)];
    const int* gq = wq + (size_t)c * 8;
    i32x4 q0 = *(const i32x4*)gq;
    i32x4 q1 = *(const i32x4*)(gq + 4);
    bf16x8 v;
    v[0] = (bf16_t)((float)q0[0] * s); v[1] = (bf16_t)((float)q0[1] * s);
    v[2] = (bf16_t)((float)q0[2] * s); v[3] = (bf16_t)((float)q0[3] * s);
    v[4] = (bf16_t)((float)q1[0] * s); v[5] = (bf16_t)((float)q1[1] * s);
    v[6] = (bf16_t)((float)q1[2] * s); v[7] = (bf16_t)((float)q1[3] * s);
    *(bf16x8*)&W[(size_t)c * 8] = v;
}

// ---------------- Pass 1b: x fp32 -> bf16 ----------------
__global__ __launch_bounds__(256) void cvt_x_kernel(
    const float* __restrict__ x, bf16_t* __restrict__ X)
{
    unsigned c = blockIdx.x * 256u + threadIdx.x;
    const float* gp = x + (size_t)c * 8;
    f32x4 f0 = *(const f32x4*)gp;
    f32x4 f1 = *(const f32x4*)(gp + 4);
    bf16x8 v;
    v[0] = (bf16_t)f0[0]; v[1] = (bf16_t)f0[1];
    v[2] = (bf16_t)f0[2]; v[3] = (bf16_t)f0[3];
    v[4] = (bf16_t)f1[0]; v[5] = (bf16_t)f1[1];
    v[6] = (bf16_t)f1[2]; v[7] = (bf16_t)f1[3];
    *(bf16x8*)&X[(size_t)c * 8] = v;
}

// ------- Pass 2: rotated-read + per-phase barrier-pair (m201-style) ---------
// C[t][o] = sum_k X[t][k] * W[o][k] + bias[o]
// Per K-tile t (cur=t&1), 4 phases, reads rotated one phase ahead; each phase:
// {reads | stage-issue -> BAR -> partial lgkmcnt (drains only PRIOR phase's
//  reads; this phase's stay in flight under the MFMA) -> setprio 16-MFMA -> BAR}
//  ph0: rd af1 (8) | stB(nxt,u0,t+1) | BAR LGKM(8)  | q00 (af0,bg0) | BAR
//  ph1: rd bg1 (4) | stB(nxt,u1,t+1) | BAR LGKM(4)  | q10           | BAR
//  ph2: stA(cur,u0+u1,t+2)           | BAR LGKM(0)  | q11           | BAR
//  ph3: vmcnt(4) BAR | rd af0',bg0' from buf[nxt] (12) | q01 (regs)
// vmcnt(4) drains A(t+1)+B(t+1) (buf[nxt] valid for ph3 reads), keeps
// A(t+2)'s 4 in flight (T4: never 0). Overwrite safety: A(cur) writes (ph2)
// after all af reads drained per-wave at ph1 LGKM + all-waves by ph1 end-BAR;
// B(nxt) writes (ph0/1) after t-1's bg reads (t-1 ph2 LGKM + BAR). Register
// banks alternate per tile (2-tile unroll, static indexing, rule #20).
// Swizzle both-sides (rule #21): linear LDS chunk (row,c8) holds global chunk
// (row, c8^(row&7)) via pre-swizzled global source; reads XOR the same.
__global__ __launch_bounds__(THREADS, 2) void gemm256q_kernel(
    const bf16_t* __restrict__ A, const bf16_t* __restrict__ B,
    const float* __restrict__ bias, float* __restrict__ out)
{
    __shared__ __align__(16) bf16_t sA[2][BM * BK];   // 2 x 32 KB
    __shared__ __align__(16) bf16_t sB[2][BN * BK];   // 2 x 32 KB -> 128 KB

    const int tid  = threadIdx.x;
    const int bm   = blockIdx.x / (N_DIM / BN);
    const int bn   = blockIdx.x % (N_DIM / BN);
    const int row0 = bm * BM;
    const int col0 = bn * BN;

    const int lane = tid & 63;
    const int wid  = tid >> 6;          // 8 waves: 2 (M) x 4 (N)
    const int wr   = (wid >> 2) * 128;  // wave row offset in tile
    const int wc   = (wid & 3) * 64;    // wave col offset in tile
    const int fr   = lane & 15;         // fragment row within 16
    const int kq   = lane >> 4;         // k-chunk quarter 0..3

    // staging: unit = 128 rows x 64 k (16 KB) = 2 issues/thread
    const int rws = tid >> 3;                         // 0..63
    const int c8s = (tid & 7) ^ (rws & 7);
    const bf16_t* srcA = A + (size_t)(row0 + rws) * K_DIM + c8s * 8;
    const bf16_t* srcB = B + (size_t)(col0 + rws) * K_DIM + c8s * 8;
    const int ldsU = (tid & ~63) * 8;                 // wave-uniform elem base

    auto stA = [&](int d, int uh, int tt) {
        const bf16_t* s = srcA + (size_t)tt * BK + (size_t)uh * 128 * K_DIM;
        gload_lds16(s,                        &sA[d][uh * 8192 + ldsU]);
        gload_lds16(s + (size_t)64 * K_DIM,   &sA[d][uh * 8192 + 4096 + ldsU]);
    };
    auto stB = [&](int d, int uh, int tt) {
        const bf16_t* s = srcB + (size_t)tt * BK + (size_t)uh * 128 * K_DIM;
        gload_lds16(s,                        &sB[d][uh * 8192 + ldsU]);
        gload_lds16(s + (size_t)64 * K_DIM,   &sB[d][uh * 8192 + 4096 + ldsU]);
    };

    f32x4 acc[8][4];
#pragma unroll
    for (int m = 0; m < 8; ++m)
#pragma unroll
        for (int n = 0; n < 4; ++n) acc[m][n] = (f32x4)0.f;

    auto rdA = [&](const bf16_t* pA, int rbase, bf16x8 (&dst)[4][2]) {
#pragma unroll
        for (int m = 0; m < 4; ++m) {
            int row = rbase + m * 16 + fr;
#pragma unroll
            for (int ks = 0; ks < 2; ++ks) {
                int kc = ks * 4 + kq;
                dst[m][ks] = *(const bf16x8*)(pA + row * BK + ((kc ^ (row & 7)) << 3));
            }
        }
    };
    auto rdB = [&](const bf16_t* pB, int rbase, bf16x8 (&dst)[2][2]) {
#pragma unroll
        for (int n = 0; n < 2; ++n) {
            int row = rbase + n * 16 + fr;
#pragma unroll
            for (int ks = 0; ks < 2; ++ks) {
                int kc = ks * 4 + kq;
                dst[n][ks] = *(const bf16x8*)(pB + row * BK + ((kc ^ (row & 7)) << 3));
            }
        }
    };
    auto mm = [&](bf16x8 (&a)[4][2], bf16x8 (&b)[2][2], int mo, int no) {
        __builtin_amdgcn_s_setprio(1);
#pragma unroll
        for (int m = 0; m < 4; ++m)
#pragma unroll
            for (int n = 0; n < 2; ++n)
#pragma unroll
                for (int ks = 0; ks < 2; ++ks)
                    acc[mo + m][no + n] = __builtin_amdgcn_mfma_f32_16x16x32_bf16(
                        a[m][ks], b[n][ks], acc[mo + m][no + n], 0, 0, 0);
        __builtin_amdgcn_s_setprio(0);
    };

    // register banks (alternate per tile; all static indexing)
    bf16x8 af0a[4][2], bg0a[2][2];
    bf16x8 af0b[4][2], bg0b[2][2];

    // ---- prologue: stage A0,B0 (buf0) + A1 (buf1); drain A0,B0 only ----
    stA(0, 0, 0); stA(0, 1, 0);
    stB(0, 0, 0); stB(0, 1, 0);
    stA(1, 0, 1); stA(1, 1, 1);
    asm volatile("s_waitcnt vmcnt(8)" ::: "memory");   // A0,B0 landed; A1 flying
    BAR();
    rdA(&sA[0][0], wr, af0a); rdB(&sB[0][0], wc, bg0a);  // tile0 ph-3 reads (12)

    auto ktile = [&](int cur, int t,
                     bf16x8 (&AF0)[4][2], bf16x8 (&BG0)[2][2],
                     bf16x8 (&AF0n)[4][2], bf16x8 (&BG0n)[2][2]) {
        const bf16_t* pA  = &sA[cur][0];
        const bf16_t* pB  = &sB[cur][0];
        const bf16_t* pAn = &sA[cur ^ 1][0];
        const bf16_t* pBn = &sB[cur ^ 1][0];
        int t1 = t + 1; if (t1 >= NT) t1 -= NT;   // tail: dummy wrap refetch
        int t2 = t + 2; if (t2 >= NT) t2 -= NT;

        bf16x8 AF1[4][2], BG1[2][2];

        // ph0: q00 | rd af1 (8) | stage B u0(t+1)
        rdA(pA, wr + 64, AF1);
        stB(cur ^ 1, 0, t1);
        BAR();
        LGKM(8);                 // drains prev ph3's 12 (af0,bg0); af1 flying
        mm(AF0, BG0, 0, 0);
        BAR();

        // ph1: q10 | rd bg1 (4) | stage B u1(t+1)
        rdB(pB, wc + 32, BG1);
        stB(cur ^ 1, 1, t1);
        BAR();
        LGKM(4);                 // drains af1; bg1 flying
        mm(AF1, BG0, 4, 0);
        BAR();

        // ph2: q11 | stage A u0+u1 (t+2 into cur; af reads all drained)
        stA(cur, 0, t2);
        stA(cur, 1, t2);
        BAR();
        LGKM(0);                 // drains bg1
        mm(AF1, BG1, 4, 2);
        BAR();

        // ph3: publish buf[nxt] | rd next af0/bg0 (12) | q01 under the drain
        asm volatile("s_waitcnt vmcnt(4)" ::: "memory");  // A(t+1),B(t+1) landed
        BAR();
        rdA(pAn, wr, AF0n); rdB(pBn, wc, BG0n);
        SBAR();
        mm(AF0, BG1, 0, 2);      // regs only; 12 reads drain under this
    };

    for (int it = 0; it < NT / 2; ++it) {
        ktile(0, it * 2,     af0a, bg0a, af0b, bg0b);
        ktile(1, it * 2 + 1, af0b, bg0b, af0a, bg0a);
    }

    // ---- epilogue: C/D layout col=lane&15, row=(lane>>4)*4+j ----
    const int crow = (lane >> 4) << 2;
    const int ccol = lane & 15;
#pragma unroll
    for (int m = 0; m < 8; ++m) {
#pragma unroll
        for (int n = 0; n < 4; ++n) {
            int col = col0 + wc + n * 16 + ccol;
            float b = bias[col];
#pragma unroll
            for (int j = 0; j < 4; ++j) {
                int row = row0 + wr + m * 16 + crow + j;
                out[(size_t)row * N_DIM + col] = acc[m][n][j] + b;
            }
        }
    }
}

// ---------------- Fallback: fused kernel (if ws too small) ----------------
#define FBM 128
#define FBN 128
#define FTHREADS 256
__global__ __launch_bounds__(FTHREADS) void dq_gemm_fused_kernel(
    const float* __restrict__ x, const int* __restrict__ wq,
    const float* __restrict__ scales, const float* __restrict__ bias,
    float* __restrict__ out)
{
    __shared__ bf16_t fA[FBM * BK];
    __shared__ bf16_t fB[FBN * BK];

    const int tid  = threadIdx.x;
    const int bm   = blockIdx.x / (N_DIM / FBN);
    const int bn   = blockIdx.x % (N_DIM / FBN);
    const int row0 = bm * FBM;
    const int col0 = bn * FBN;
    const int lane = tid & 63;
    const int wid  = tid >> 6;
    const int wr   = (wid >> 1) * 64;
    const int wc   = (wid & 1) * 64;
    const int fr   = lane & 15;
    const int fk   = (lane >> 4) << 3;

    f32x4 acc[4][4];
#pragma unroll
    for (int m = 0; m < 4; ++m)
#pragma unroll
        for (int n = 0; n < 4; ++n) acc[m][n] = (f32x4)0.f;

    for (int kt = 0; kt < K_DIM / BK; ++kt) {
        const int kb = kt * BK;
#pragma unroll
        for (int c = 0; c < 4; ++c) {
            int i  = c * FTHREADS + tid;
            int r  = i >> 3;
            int k0 = (i & 7) << 3;
            const float* gp = x + (size_t)(row0 + r) * K_DIM + kb + k0;
            f32x4 f0 = *(const f32x4*)gp;
            f32x4 f1 = *(const f32x4*)(gp + 4);
            bf16x8 v;
            v[0] = (bf16_t)f0[0]; v[1] = (bf16_t)f0[1];
            v[2] = (bf16_t)f0[2]; v[3] = (bf16_t)f0[3];
            v[4] = (bf16_t)f1[0]; v[5] = (bf16_t)f1[1];
            v[6] = (bf16_t)f1[2]; v[7] = (bf16_t)f1[3];
            *(bf16x8*)&fA[r * BK + (k0 ^ ((r & 7) << 3))] = v;
        }
#pragma unroll
        for (int c = 0; c < 4; ++c) {
            int i  = c * FTHREADS + tid;
            int r  = i >> 3;
            int k0 = (i & 7) << 3;
            int o  = col0 + r;
            const int* gq = wq + (size_t)o * K_DIM + kb + k0;
            i32x4 q0 = *(const i32x4*)gq;
            i32x4 q1 = *(const i32x4*)(gq + 4);
            float s = scales[o * NBLK + ((kb + k0) >> 5)];
            bf16x8 v;
            v[0] = (bf16_t)((float)q0[0] * s); v[1] = (bf16_t)((float)q0[1] * s);
            v[2] = (bf16_t)((float)q0[2] * s); v[3] = (bf16_t)((float)q0[3] * s);
            v[4] = (bf16_t)((float)q1[0] * s); v[5] = (bf16_t)((float)q1[1] * s);
            v[6] = (bf16_t)((float)q1[2] * s); v[7] = (bf16_t)((float)q1[3] * s);
            *(bf16x8*)&fB[r * BK + (k0 ^ ((r & 7) << 3))] = v;
        }
        __syncthreads();
#pragma unroll
        for (int ks = 0; ks < 2; ++ks) {
            bf16x8 af[4], bg[4];
#pragma unroll
            for (int m = 0; m < 4; ++m) {
                int r = wr + m * 16 + fr;
                af[m] = *(const bf16x8*)&fA[r * BK + ((ks * 32 + fk) ^ ((r & 7) << 3))];
            }
#pragma unroll
            for (int n = 0; n < 4; ++n) {
                int r = wc + n * 16 + fr;
                bg[n] = *(const bf16x8*)&fB[r * BK + ((ks * 32 + fk) ^ ((r & 7) << 3))];
            }
#pragma unroll
            for (int m = 0; m < 4; ++m)
#pragma unroll
                for (int n = 0; n < 4; ++n)
                    acc[m][n] = __builtin_amdgcn_mfma_f32_16x16x32_bf16(
                        af[m], bg[n], acc[m][n], 0, 0, 0);
        }
        __syncthreads();
    }

    const int crow = (lane >> 4) << 2;
    const int ccol = lane & 15;
#pragma unroll
    for (int m = 0; m < 4; ++m) {
#pragma unroll
        for (int n = 0; n < 4; ++n) {
            int col = col0 + wc + n * 16 + ccol;
            float b = bias[col];
#pragma unroll
            for (int j = 0; j < 4; ++j) {
                int row = row0 + wr + m * 16 + crow + j;
                out[(size_t)row * N_DIM + col] = acc[m][n][j] + b;
            }
        }
    }
}

extern "C" void kernel_launch(void* const* d_in, const int* in_sizes, int n_in,
                              void* d_out, int out_size, void* d_ws, size_t ws_size,
                              hipStream_t stream) {
    const float* x      = (const float*)d_in[0];
    const int*   wq     = (const int*)d_in[1];
    const float* scales = (const float*)d_in[2];
    const float* bias   = (const float*)d_in[3];
    float*       out    = (float*)d_out;

    if (ws_size >= W_BYTES + X_BYTES) {
        bf16_t* W = (bf16_t*)d_ws;
        bf16_t* X = (bf16_t*)((char*)d_ws + W_BYTES);
        dequant_w_kernel<<<dim3(N_DIM * K_DIM / 8 / 256), dim3(256), 0, stream>>>(wq, scales, W);
        cvt_x_kernel<<<dim3(M_DIM * K_DIM / 8 / 256), dim3(256), 0, stream>>>(x, X);
        gemm256q_kernel<<<dim3((M_DIM / BM) * (N_DIM / BN)), dim3(THREADS), 0, stream>>>(X, W, bias, out);
    } else {
        dq_gemm_fused_kernel<<<dim3((M_DIM / FBM) * (N_DIM / FBN)), dim3(FTHREADS), 0, stream>>>(
            x, wq, scales, bias, out);
    }
}

// Round 10
// 325.513 us; speedup vs baseline: 1.0184x; 1.0184x over previous
//
#include <hip/hip_runtime.h>
#include <hip/hip_bf16.h>

typedef __bf16 bf16_t;
typedef __bf16 bf16x8 __attribute__((ext_vector_type(8)));
typedef float  f32x4  __attribute__((ext_vector_type(4)));
typedef int    i32x4  __attribute__((ext_vector_type(4)));

#define M_DIM 4096
#define N_DIM 12288
#define K_DIM 3072
#define NBLK  96      // K_DIM / 32 quant blocks per output row

#define BM 256
#define BN 256
#define BK 64
#define THREADS 512
#define NT (K_DIM / BK)   // 48 K-tiles

// ws layout: W_bf16 [N][K] at 0 (75.5 MB), X_bf16 [M][K] after (25.2 MB)
#define W_BYTES ((size_t)N_DIM * K_DIM * 2)
#define X_BYTES ((size_t)M_DIM * K_DIM * 2)

#define BAR()   asm volatile("s_barrier" ::: "memory")
#define SBAR()  __builtin_amdgcn_sched_barrier(0)
// SchedGroupMask (m137): MFMA=0x8, DS_READ=0x100
#define SG(mask, n) __builtin_amdgcn_sched_group_barrier(mask, n, 0)

__device__ __forceinline__ void gload_lds16(const void* g, void* l) {
    // async global->LDS, 16B/lane; LDS dest = wave-uniform base + lane*16
    __builtin_amdgcn_global_load_lds(
        (const __attribute__((address_space(1))) unsigned int*)g,
        (__attribute__((address_space(3))) unsigned int*)l, 16, 0, 0);
}

// ---------------- Pass 1a: dequant Q8_0 weights -> bf16 ----------------
__global__ __launch_bounds__(256) void dequant_w_kernel(
    const int* __restrict__ wq, const float* __restrict__ scales,
    bf16_t* __restrict__ W)
{
    unsigned c = blockIdx.x * 256u + threadIdx.x;   // 8-elem chunk id
    unsigned o  = c / 384u;                         // 384 chunks per row
    unsigned kc = c - o * 384u;
    float s = scales[o * NBLK + (kc >> 2)];
    const int* gq = wq + (size_t)c * 8;
    i32x4 q0 = *(const i32x4*)gq;
    i32x4 q1 = *(const i32x4*)(gq + 4);
    bf16x8 v;
    v[0] = (bf16_t)((float)q0[0] * s); v[1] = (bf16_t)((float)q0[1] * s);
    v[2] = (bf16_t)((float)q0[2] * s); v[3] = (bf16_t)((float)q0[3] * s);
    v[4] = (bf16_t)((float)q1[0] * s); v[5] = (bf16_t)((float)q1[1] * s);
    v[6] = (bf16_t)((float)q1[2] * s); v[7] = (bf16_t)((float)q1[3] * s);
    *(bf16x8*)&W[(size_t)c * 8] = v;
}

// ---------------- Pass 1b: x fp32 -> bf16 ----------------
__global__ __launch_bounds__(256) void cvt_x_kernel(
    const float* __restrict__ x, bf16_t* __restrict__ X)
{
    unsigned c = blockIdx.x * 256u + threadIdx.x;
    const float* gp = x + (size_t)c * 8;
    f32x4 f0 = *(const f32x4*)gp;
    f32x4 f1 = *(const f32x4*)(gp + 4);
    bf16x8 v;
    v[0] = (bf16_t)f0[0]; v[1] = (bf16_t)f0[1];
    v[2] = (bf16_t)f0[2]; v[3] = (bf16_t)f0[3];
    v[4] = (bf16_t)f1[0]; v[5] = (bf16_t)f1[1];
    v[6] = (bf16_t)f1[2]; v[7] = (bf16_t)f1[3];
    *(bf16x8*)&X[(size_t)c * 8] = v;
}

// ------- Pass 2: rotated-read pipeline (r8) + SGB ds_read/MFMA interleave ----
// C[t][o] = sum_k X[t][k] * W[o][k] + bias[o]
// Round-8 schedule (best measured: 269us / 52% MfmaUtil), with the per-phase
// {read-burst then MFMA-burst} serialization replaced by sched_group_barrier
// 1:1-ish DS_READ/MFMA interleave so the LDS pipe drains UNDER the MFMA burst
// within a wave (T19; reads feed the NEXT phase, no dep on current MFMAs).
//  phA: [af1(8) ds | stB u0 | 16 MFMA q00] interleaved  | SBAR
//  phB: [bg1(4) ds | stB u1 | 16 MFMA q10] interleaved  | BAR
//  phC: stA u0+u1(t+2)->cur | 16 MFMA q11 | vmcnt(4) | BAR
//  phD: [af0',bg0'(12) ds from nxt | 16 MFMA q01] interleaved
// Safety: all ds/gload ops are memory ops -> pinned by the "memory"-clobber
// BAR/vmcnt asm (can't cross); MFMA reg-only hoisting across BARs is benign.
// A(cur) overwrite (phC) is after all af reads per-wave (reg deps) + phB BAR.
// vmcnt(4) drains A(t+1)+B(t+1), keeps A(t+2)'s 4 in flight (never 0).
// Swizzle both-sides (rule #21): linear LDS chunk (row,c8) holds global chunk
// (row, c8^(row&7)) via pre-swizzled global source; reads XOR the same.
__global__ __launch_bounds__(THREADS, 2) void gemm256s_kernel(
    const bf16_t* __restrict__ A, const bf16_t* __restrict__ B,
    const float* __restrict__ bias, float* __restrict__ out)
{
    __shared__ __align__(16) bf16_t sA[2][BM * BK];   // 2 x 32 KB
    __shared__ __align__(16) bf16_t sB[2][BN * BK];   // 2 x 32 KB -> 128 KB

    const int tid  = threadIdx.x;
    const int bm   = blockIdx.x / (N_DIM / BN);
    const int bn   = blockIdx.x % (N_DIM / BN);
    const int row0 = bm * BM;
    const int col0 = bn * BN;

    const int lane = tid & 63;
    const int wid  = tid >> 6;          // 8 waves: 2 (M) x 4 (N)
    const int wr   = (wid >> 2) * 128;  // wave row offset in tile
    const int wc   = (wid & 3) * 64;    // wave col offset in tile
    const int fr   = lane & 15;         // fragment row within 16
    const int kq   = lane >> 4;         // k-chunk quarter 0..3

    // staging: unit = 128 rows x 64 k (16 KB) = 2 issues/thread
    const int rws = tid >> 3;                         // 0..63
    const int c8s = (tid & 7) ^ (rws & 7);
    const bf16_t* srcA = A + (size_t)(row0 + rws) * K_DIM + c8s * 8;
    const bf16_t* srcB = B + (size_t)(col0 + rws) * K_DIM + c8s * 8;
    const int ldsU = (tid & ~63) * 8;                 // wave-uniform elem base

    auto stA = [&](int d, int uh, int tt) {
        const bf16_t* s = srcA + (size_t)tt * BK + (size_t)uh * 128 * K_DIM;
        gload_lds16(s,                        &sA[d][uh * 8192 + ldsU]);
        gload_lds16(s + (size_t)64 * K_DIM,   &sA[d][uh * 8192 + 4096 + ldsU]);
    };
    auto stB = [&](int d, int uh, int tt) {
        const bf16_t* s = srcB + (size_t)tt * BK + (size_t)uh * 128 * K_DIM;
        gload_lds16(s,                        &sB[d][uh * 8192 + ldsU]);
        gload_lds16(s + (size_t)64 * K_DIM,   &sB[d][uh * 8192 + 4096 + ldsU]);
    };

    f32x4 acc[8][4];
#pragma unroll
    for (int m = 0; m < 8; ++m)
#pragma unroll
        for (int n = 0; n < 4; ++n) acc[m][n] = (f32x4)0.f;

    auto rdA = [&](const bf16_t* pA, int rbase, bf16x8 (&dst)[4][2]) {
#pragma unroll
        for (int m = 0; m < 4; ++m) {
            int row = rbase + m * 16 + fr;
#pragma unroll
            for (int ks = 0; ks < 2; ++ks) {
                int kc = ks * 4 + kq;
                dst[m][ks] = *(const bf16x8*)(pA + row * BK + ((kc ^ (row & 7)) << 3));
            }
        }
    };
    auto rdB = [&](const bf16_t* pB, int rbase, bf16x8 (&dst)[2][2]) {
#pragma unroll
        for (int n = 0; n < 2; ++n) {
            int row = rbase + n * 16 + fr;
#pragma unroll
            for (int ks = 0; ks < 2; ++ks) {
                int kc = ks * 4 + kq;
                dst[n][ks] = *(const bf16x8*)(pB + row * BK + ((kc ^ (row & 7)) << 3));
            }
        }
    };
    auto mm = [&](bf16x8 (&a)[4][2], bf16x8 (&b)[2][2], int mo, int no) {
        __builtin_amdgcn_s_setprio(1);
#pragma unroll
        for (int m = 0; m < 4; ++m)
#pragma unroll
            for (int n = 0; n < 2; ++n)
#pragma unroll
                for (int ks = 0; ks < 2; ++ks)
                    acc[mo + m][no + n] = __builtin_amdgcn_mfma_f32_16x16x32_bf16(
                        a[m][ks], b[n][ks], acc[mo + m][no + n], 0, 0, 0);
        __builtin_amdgcn_s_setprio(0);
    };

    // SGB interleave patterns: nrd ds_reads woven into 16 MFMA
    auto weave8 = [] {                   // 8 reads: MFMA2 + 8x(DS1,MFMA1) + MFMA6
        SG(0x8, 2);
#pragma unroll
        for (int i = 0; i < 8; ++i) { SG(0x100, 1); SG(0x8, 1); }
        SG(0x8, 6);
    };
    auto weave4 = [] {                   // 4 reads: MFMA2 + 4x(DS1,MFMA2) + MFMA6
        SG(0x8, 2);
#pragma unroll
        for (int i = 0; i < 4; ++i) { SG(0x100, 1); SG(0x8, 2); }
        SG(0x8, 6);
    };
    auto weave12 = [] {                  // 12 reads: MFMA1 + 12x(DS1,MFMA1) + MFMA3
        SG(0x8, 1);
#pragma unroll
        for (int i = 0; i < 12; ++i) { SG(0x100, 1); SG(0x8, 1); }
        SG(0x8, 3);
    };

    // register banks (alternate per tile; all static indexing)
    bf16x8 af0a[4][2], af1a[4][2], bg0a[2][2], bg1a[2][2];
    bf16x8 af0b[4][2], af1b[4][2], bg0b[2][2], bg1b[2][2];

    // ---- prologue: tile0 all units + tile1 A units; drain tile0; read 12 ----
    stA(0, 0, 0); stA(0, 1, 0); stB(0, 0, 0); stB(0, 1, 0);
    stA(1, 0, 1); stA(1, 1, 1);
    asm volatile("s_waitcnt vmcnt(4)" ::: "memory");
    BAR();
    rdA(&sA[0][0], wr, af0a); rdB(&sB[0][0], wc, bg0a);

    auto ktile = [&](int cur, int t,
                     bf16x8 (&AF0)[4][2], bf16x8 (&AF1)[4][2],
                     bf16x8 (&BG0)[2][2], bf16x8 (&BG1)[2][2],
                     bf16x8 (&AF0n)[4][2], bf16x8 (&BG0n)[2][2]) {
        const bf16_t* pA  = &sA[cur][0];
        const bf16_t* pB  = &sB[cur][0];
        const bf16_t* pAn = &sA[cur ^ 1][0];
        const bf16_t* pBn = &sB[cur ^ 1][0];
        int t1 = t + 1; if (t1 >= NT) t1 -= NT;   // tail: dummy wrap refetch
        int t2 = t + 2; if (t2 >= NT) t2 -= NT;

        // phA: q00 with af1 reads woven in | stage B u0
        rdA(pA, wr + 64, AF1);
        stB(cur ^ 1, 0, t1);
        mm(AF0, BG0, 0, 0);
        weave8();
        SBAR();

        // phB: q10 with bg1 reads woven in | stage B u1 | BAR
        rdB(pB, wc + 32, BG1);
        stB(cur ^ 1, 1, t1);
        mm(AF1, BG0, 4, 0);
        weave4();
        BAR();

        // phC: q11 | stage A u0+u1 (t+2 into cur) | vmcnt(4) BAR
        stA(cur, 0, t2);
        stA(cur, 1, t2);
        SBAR();
        mm(AF1, BG1, 4, 2);
        SBAR();
        asm volatile("s_waitcnt vmcnt(4)" ::: "memory");
        BAR();

        // phD: q01 with next tile's 12 reads woven in
        rdA(pAn, wr, AF0n); rdB(pBn, wc, BG0n);
        mm(AF0, BG1, 0, 2);
        weave12();
    };

    for (int it = 0; it < NT / 2; ++it) {
        ktile(0, it * 2,     af0a, af1a, bg0a, bg1a, af0b, bg0b);
        ktile(1, it * 2 + 1, af0b, af1b, bg0b, bg1b, af0a, bg0a);
    }

    // ---- epilogue: C/D layout col=lane&15, row=(lane>>4)*4+j ----
    const int crow = (lane >> 4) << 2;
    const int ccol = lane & 15;
#pragma unroll
    for (int m = 0; m < 8; ++m) {
#pragma unroll
        for (int n = 0; n < 4; ++n) {
            int col = col0 + wc + n * 16 + ccol;
            float b = bias[col];
#pragma unroll
            for (int j = 0; j < 4; ++j) {
                int row = row0 + wr + m * 16 + crow + j;
                out[(size_t)row * N_DIM + col] = acc[m][n][j] + b;
            }
        }
    }
}

// ---------------- Fallback: fused kernel (if ws too small) ----------------
#define FBM 128
#define FBN 128
#define FTHREADS 256
__global__ __launch_bounds__(FTHREADS) void dq_gemm_fused_kernel(
    const float* __restrict__ x, const int* __restrict__ wq,
    const float* __restrict__ scales, const float* __restrict__ bias,
    float* __restrict__ out)
{
    __shared__ bf16_t fA[FBM * BK];
    __shared__ bf16_t fB[FBN * BK];

    const int tid  = threadIdx.x;
    const int bm   = blockIdx.x / (N_DIM / FBN);
    const int bn   = blockIdx.x % (N_DIM / FBN);
    const int row0 = bm * FBM;
    const int col0 = bn * FBN;
    const int lane = tid & 63;
    const int wid  = tid >> 6;
    const int wr   = (wid >> 1) * 64;
    const int wc   = (wid & 1) * 64;
    const int fr   = lane & 15;
    const int fk   = (lane >> 4) << 3;

    f32x4 acc[4][4];
#pragma unroll
    for (int m = 0; m < 4; ++m)
#pragma unroll
        for (int n = 0; n < 4; ++n) acc[m][n] = (f32x4)0.f;

    for (int kt = 0; kt < K_DIM / BK; ++kt) {
        const int kb = kt * BK;
#pragma unroll
        for (int c = 0; c < 4; ++c) {
            int i  = c * FTHREADS + tid;
            int r  = i >> 3;
            int k0 = (i & 7) << 3;
            const float* gp = x + (size_t)(row0 + r) * K_DIM + kb + k0;
            f32x4 f0 = *(const f32x4*)gp;
            f32x4 f1 = *(const f32x4*)(gp + 4);
            bf16x8 v;
            v[0] = (bf16_t)f0[0]; v[1] = (bf16_t)f0[1];
            v[2] = (bf16_t)f0[2]; v[3] = (bf16_t)f0[3];
            v[4] = (bf16_t)f1[0]; v[5] = (bf16_t)f1[1];
            v[6] = (bf16_t)f1[2]; v[7] = (bf16_t)f1[3];
            *(bf16x8*)&fA[r * BK + (k0 ^ ((r & 7) << 3))] = v;
        }
#pragma unroll
        for (int c = 0; c < 4; ++c) {
            int i  = c * FTHREADS + tid;
            int r  = i >> 3;
            int k0 = (i & 7) << 3;
            int o  = col0 + r;
            const int* gq = wq + (size_t)o * K_DIM + kb + k0;
            i32x4 q0 = *(const i32x4*)gq;
            i32x4 q1 = *(const i32x4*)(gq + 4);
            float s = scales[o * NBLK + ((kb + k0) >> 5)];
            bf16x8 v;
            v[0] = (bf16_t)((float)q0[0] * s); v[1] = (bf16_t)((float)q0[1] * s);
            v[2] = (bf16_t)((float)q0[2] * s); v[3] = (bf16_t)((float)q0[3] * s);
            v[4] = (bf16_t)((float)q1[0] * s); v[5] = (bf16_t)((float)q1[1] * s);
            v[6] = (bf16_t)((float)q1[2] * s); v[7] = (bf16_t)((float)q1[3] * s);
            *(bf16x8*)&fB[r * BK + (k0 ^ ((r & 7) << 3))] = v;
        }
        __syncthreads();
#pragma unroll
        for (int ks = 0; ks < 2; ++ks) {
            bf16x8 af[4], bg[4];
#pragma unroll
            for (int m = 0; m < 4; ++m) {
                int r = wr + m * 16 + fr;
                af[m] = *(const bf16x8*)&fA[r * BK + ((ks * 32 + fk) ^ ((r & 7) << 3))];
            }
#pragma unroll
            for (int n = 0; n < 4; ++n) {
                int r = wc + n * 16 + fr;
                bg[n] = *(const bf16x8*)&fB[r * BK + ((ks * 32 + fk) ^ ((r & 7) << 3))];
            }
#pragma unroll
            for (int m = 0; m < 4; ++m)
#pragma unroll
                for (int n = 0; n < 4; ++n)
                    acc[m][n] = __builtin_amdgcn_mfma_f32_16x16x32_bf16(
                        af[m], bg[n], acc[m][n], 0, 0, 0);
        }
        __syncthreads();
    }

    const int crow = (lane >> 4) << 2;
    const int ccol = lane & 15;
#pragma unroll
    for (int m = 0; m < 4; ++m) {
#pragma unroll
        for (int n = 0; n < 4; ++n) {
            int col = col0 + wc + n * 16 + ccol;
            float b = bias[col];
#pragma unroll
            for (int j = 0; j < 4; ++j) {
                int row = row0 + wr + m * 16 + crow + j;
                out[(size_t)row * N_DIM + col] = acc[m][n][j] + b;
            }
        }
    }
}

extern "C" void kernel_launch(void* const* d_in, const int* in_sizes, int n_in,
                              void* d_out, int out_size, void* d_ws, size_t ws_size,
                              hipStream_t stream) {
    const float* x      = (const float*)d_in[0];
    const int*   wq     = (const int*)d_in[1];
    const float* scales = (const float*)d_in[2];
    const float* bias   = (const float*)d_in[3];
    float*       out    = (float*)d_out;

    if (ws_size >= W_BYTES + X_BYTES) {
        bf16_t* W = (bf16_t*)d_ws;
        bf16_t* X = (bf16_t*)((char*)d_ws + W_BYTES);
        dequant_w_kernel<<<dim3(N_DIM * K_DIM / 8 / 256), dim3(256), 0, stream>>>(wq, scales, W);
        cvt_x_kernel<<<dim3(M_DIM * K_DIM / 8 / 256), dim3(256), 0, stream>>>(x, X);
        gemm256s_kernel<<<dim3((M_DIM / BM) * (N_DIM / BN)), dim3(THREADS), 0, stream>>>(X, W, bias, out);
    } else {
        dq_gemm_fused_kernel<<<dim3((M_DIM / FBM) * (N_DIM / FBN)), dim3(FTHREADS), 0, stream>>>(
            x, wq, scales, bias, out);
    }
}